// Round 1
// 602.887 us; speedup vs baseline: 1.0403x; 1.0403x over previous
//
#include <hip/hip_runtime.h>
#include <hip/hip_bf16.h>
#include <hip/hip_fp16.h>
#include <math.h>

// Problem constants
#define N_CARDS 10000
#define HIDDEN  128
#define E       256
#define BATCH   16384
#define L       8
#define NH      4
#define HD      64

typedef __attribute__((ext_vector_type(8))) short short8;
typedef __attribute__((ext_vector_type(4))) float f32x4;
typedef _Float16 __attribute__((ext_vector_type(8))) half8;
typedef _Float16 __attribute__((ext_vector_type(2))) h2v;
typedef unsigned short ust;

__device__ __forceinline__ f32x4 mfmaf16(half8 a, half8 b, f32x4 c) {
  return __builtin_amdgcn_mfma_f32_16x16x32_f16(a, b, c, 0, 0, 0);
}

// fp16 dot over 64 dims, f32 accumulate (v_dot2_f32_f16 when available)
__device__ __forceinline__ float dot64(const __half* q, const __half* k) {
  float s = 0.f;
#pragma unroll
  for (int d = 0; d < 8; ++d) {
    short8 qa = *(const short8*)(q + d * 8);
    short8 kb = *(const short8*)(k + d * 8);
    const h2v* q2 = (const h2v*)&qa;
    const h2v* k2 = (const h2v*)&kb;
#pragma unroll
    for (int m = 0; m < 4; ++m) {
#if __has_builtin(__builtin_amdgcn_fdot2)
      s = __builtin_amdgcn_fdot2(q2[m], k2[m], s, false);
#else
      s += (float)q2[m][0] * (float)k2[m][0] + (float)q2[m][1] * (float)k2[m][1];
#endif
    }
  }
  return s;
}

// ---------------------------------------------------------------------------
// K1: fused prep: emb->fp16 (blocks 0..4999), in_w->fp16 (5000..5383),
// w2 -> fp16 row-major copy (5384..5447)  [MFMA B-operand layout]
// ---------------------------------------------------------------------------
__global__ __launch_bounds__(256) void prep_all(
    const float* __restrict__ xr, const float* __restrict__ xi,
    const float* __restrict__ wmy, const float* __restrict__ wop,
    const float* __restrict__ w2,
    __half* __restrict__ embf, __half* __restrict__ wbf,
    __half* __restrict__ w2h) {
  int bid = blockIdx.x;
  int tid = threadIdx.x;
  if (bid < 5000) {
    int c = bid * 2 + (tid >> 7);
    int d = tid & 127;
    float r  = xr[c * HIDDEN + d];
    float im = xi[c * HIDDEN + d];
    float amp = sqrtf(r * r + im * im + 1e-8f);
    float ph  = atan2f(im, r);
    embf[c * E + d]          = __float2half(amp);
    embf[c * E + HIDDEN + d] = __float2half(ph);
  } else if (bid < 5384) {
    int idx = (bid - 5000) * 256 + tid;   // float4 over 1536*256/4
    int row = idx >> 6, c4 = idx & 63;
    const float* src = (row < 768) ? (wmy + (size_t)row * 256)
                                   : (wop + (size_t)(row - 768) * 256);
    float4 v = *(const float4*)(src + c4 * 4);
    __half h[4] = {__float2half(v.x), __float2half(v.y),
                   __float2half(v.z), __float2half(v.w)};
    *(uint2*)&wbf[(size_t)row * 256 + c4 * 4] = *(const uint2*)h;
  } else {
    int idx = (bid - 5384) * 256 + tid;   // 0..16383 over w2[64][256]
    w2h[idx] = __float2half(w2[idx]);
  }
}

// ---------------------------------------------------------------------------
// K2: projection GEMM, pure fp16 MFMA (f32 accumulate); OUTPUT FP16.
// 128x128 tile, BK=64, 4 waves 2x2, 4x4 MFMA. LDS 36 KB -> 4 blocks/CU.
// ---------------------------------------------------------------------------
#define PSTR 72
__global__ __launch_bounds__(256) void proj_mfma(
    const __half* __restrict__ embf, const __half* __restrict__ wbf,
    const float* __restrict__ bmy, const float* __restrict__ bop,
    __half* __restrict__ proj) {
  __shared__ __align__(16) __half sA[128 * PSTR];
  __shared__ __align__(16) __half sB[128 * PSTR];
  int m0 = blockIdx.x * 128;
  int n0 = blockIdx.y * 128;
  int tid = threadIdx.x;
  int w = tid >> 6, lane = tid & 63;
  int wm = w >> 1, wn = w & 1;
  int lrow = lane & 15, lq = lane >> 4;

  f32x4 acc[4][4] = {};

  for (int kb = 0; kb < 256; kb += 64) {
#pragma unroll
    for (int rep = 0; rep < 4; ++rep) {
      int idx = rep * 256 + tid;       // 0..1023
      int row = idx >> 3, ch = (idx & 7) * 8;
      int gm = m0 + row;
      half8 av = {};
      if (gm < N_CARDS) av = *(const half8*)&embf[(size_t)gm * 256 + kb + ch];
      *(half8*)&sA[row * PSTR + ch] = av;
      int gn = n0 + row;
      *(half8*)&sB[row * PSTR + ch] = *(const half8*)&wbf[(size_t)gn * 256 + kb + ch];
    }
    __syncthreads();
#pragma unroll
    for (int ks = 0; ks < 2; ++ks) {
      int ko = ks * 32 + lq * 8;
      half8 a[4], b[4];
#pragma unroll
      for (int i = 0; i < 4; ++i) {
        a[i] = *(const half8*)&sA[(wm * 64 + i * 16 + lrow) * PSTR + ko];
        b[i] = *(const half8*)&sB[(wn * 64 + i * 16 + lrow) * PSTR + ko];
      }
#pragma unroll
      for (int i = 0; i < 4; ++i)
#pragma unroll
        for (int j = 0; j < 4; ++j)
          acc[i][j] = mfmaf16(a[i], b[j], acc[i][j]);
    }
    __syncthreads();
  }

  const float* bias = (n0 < 768) ? bmy : bop;
  int nbase = (n0 < 768) ? n0 : n0 - 768;
#pragma unroll
  for (int j = 0; j < 4; ++j) {
    int ncol = wn * 64 + j * 16 + lrow;
    float bv = bias[nbase + ncol];
#pragma unroll
    for (int i = 0; i < 4; ++i) {
      int mrow0 = m0 + wm * 64 + i * 16 + lq * 4;
#pragma unroll
      for (int r = 0; r < 4; ++r) {
        int m = mrow0 + r;
        if (m < N_CARDS)
          proj[(size_t)m * 1536 + n0 + ncol] = __float2half(acc[i][j][r] + bv);
      }
    }
  }
}

// ---------------------------------------------------------------------------
// K2b: Wcomb fp16 [i][k] (k in [0,512)); bias_c fused (blockIdx.x == 256).
// 4 accumulators to break the serial FMA dependence chain.
// ---------------------------------------------------------------------------
__global__ __launch_bounds__(256) void combine_w(
    const float* __restrict__ w1, const float* __restrict__ b1,
    const float* __restrict__ owmy, const float* __restrict__ owop,
    const float* __restrict__ obm, const float* __restrict__ obo,
    __half* __restrict__ wcf, float* __restrict__ bias_c) {
  int i = blockIdx.x;
  int half_ = blockIdx.y;
  if (i == 256) {
    if (half_) return;
    int t = threadIdx.x;
    float s = b1[t];
    for (int f = 0; f < 256; f += 4) {
      float4 wa = *(const float4*)&w1[(size_t)t * 512 + f];
      float4 ba = *(const float4*)&obm[f];
      float4 wb = *(const float4*)&w1[(size_t)t * 512 + 256 + f];
      float4 bo = *(const float4*)&obo[f];
      s += wa.x * ba.x + wa.y * ba.y + wa.z * ba.z + wa.w * ba.w;
      s += wb.x * bo.x + wb.y * bo.y + wb.z * bo.z + wb.w * bo.w;
    }
    bias_c[t] = s;
    return;
  }
  int kp = threadIdx.x;
  const float* ow = half_ ? owop : owmy;
  const float* w1r = w1 + (size_t)i * 512 + half_ * 256;
  float s0 = 0.f, s1 = 0.f, s2 = 0.f, s3 = 0.f;
  for (int f = 0; f < 256; f += 4) {
    s0 += w1r[f + 0] * ow[(size_t)(f + 0) * 256 + kp];
    s1 += w1r[f + 1] * ow[(size_t)(f + 1) * 256 + kp];
    s2 += w1r[f + 2] * ow[(size_t)(f + 2) * 256 + kp];
    s3 += w1r[f + 3] * ow[(size_t)(f + 3) * 256 + kp];
  }
  wcf[(size_t)i * 512 + half_ * 256 + kp] = __float2half((s0 + s1) + (s2 + s3));
}

// ---------------------------------------------------------------------------
// K3: per-batch attention. Cards broadcast via __shfl (no LDS, no 1st
// barrier); adj (HBM-random, longest latency) issued first so it overlaps
// the proj gather. fp16 Q/K in LDS, scores via v_dot2_f32_f16, __expf
// softmax; V via __half2 direct-global; mean stored fp16.
// ---------------------------------------------------------------------------
#define AST 264
__global__ __launch_bounds__(256) void attn_kernel(
    const __half* __restrict__ proj,
    const int* __restrict__ my_decks, const int* __restrict__ op_decks,
    const int* __restrict__ adj,
    __half* __restrict__ meanf) {
  __shared__ __align__(16) __half tab[4 * 8 * AST];
  __shared__ float biasm[8][8];
  __shared__ float wbar[2][NH][8];

  int b = blockIdx.x;
  int tid = threadIdx.x;
  int w    = tid >> 6;
  int lane = tid & 63;

  // every wave loads all 16 cards into lanes 0..15 (L1-served after wave 0)
  int card16 = 0;
  if (lane < 16) {
    const int* dp = (lane < 8) ? (my_decks + b * L + lane)
                               : (op_decks + b * L + lane - 8);
    card16 = *dp;
  }

  // adj bias (wave 0 only) — issue BEFORE gather so HBM latency overlaps
  if (w == 0) {
    int ci = __shfl(card16, lane >> 3);        // cards[i]
    int cj = __shfl(card16, 8 + (lane & 7));   // cards[8+j]
    int m = adj[(size_t)ci * N_CARDS + cj];
    biasm[lane >> 3][lane & 7] = (m > 0) ? 0.0f : -10000.0f;
  }

  // gather qmy(0,my), kmy(1,op), qop(3,op), kop(4,my) fp16 into LDS
#pragma unroll
  for (int it = 0; it < 4; ++it) {
    int t   = it;
    int r   = (tid >> 5) & 7;
    int c8  = tid & 31;
    int tp  = (t == 0) ? 0 : (t == 1) ? 1 : (t == 2) ? 3 : 4;
    int useMy = (t == 0) | (t == 3);
    int card = __shfl(card16, useMy ? r : (8 + r));
    uint4 u = *(const uint4*)(proj + (size_t)card * 1536 + tp * 256 + c8 * 8);
    *(uint4*)&tab[(t * 8 + r) * AST + c8 * 8] = u;
  }
  __syncthreads();

  int i = lane >> 3, j = lane & 7;
  {
    float s = dot64(&tab[(0 * 8 + i) * AST + w * HD],
                    &tab[(1 * 8 + j) * AST + w * HD]);
    s = s * 0.125f + biasm[i][j];
    float mx = s;
    mx = fmaxf(mx, __shfl_xor(mx, 1));
    mx = fmaxf(mx, __shfl_xor(mx, 2));
    mx = fmaxf(mx, __shfl_xor(mx, 4));
    float e = __expf(s - mx);
    float sum = e;
    sum += __shfl_xor(sum, 1); sum += __shfl_xor(sum, 2); sum += __shfl_xor(sum, 4);
    float a = e / sum;
    a += __shfl_xor(a, 8); a += __shfl_xor(a, 16); a += __shfl_xor(a, 32);
    if (lane < 8) wbar[0][w][lane] = a * 0.125f;
  }
  {
    float s = dot64(&tab[(2 * 8 + i) * AST + w * HD],
                    &tab[(3 * 8 + j) * AST + w * HD]);
    s = s * 0.125f + biasm[j][i];
    float mx = s;
    mx = fmaxf(mx, __shfl_xor(mx, 1));
    mx = fmaxf(mx, __shfl_xor(mx, 2));
    mx = fmaxf(mx, __shfl_xor(mx, 4));
    float e = __expf(s - mx);
    float sum = e;
    sum += __shfl_xor(sum, 1); sum += __shfl_xor(sum, 2); sum += __shfl_xor(sum, 4);
    float a = e / sum;
    a += __shfl_xor(a, 8); a += __shfl_xor(a, 16); a += __shfl_xor(a, 32);
    if (lane < 8) wbar[1][w][lane] = a * 0.125f;
  }
  __syncthreads();

  // PV: side 0 -> mean_my (v from op cards, blk 2), side 1 -> mean_op
  // (v from my cards, blk 5). half2 loads, paired fp16 stores.
  {
    int p = tid & 127, side = tid >> 7;
    int h = p >> 5;   // head of elements 2p, 2p+1
    int tp = side ? 5 : 2;
    float s0 = 0.f, s1 = 0.f;
#pragma unroll
    for (int jj = 0; jj < 8; ++jj) {
      int card = __shfl(card16, side ? jj : (8 + jj));
      __half2 v2 = *(const __half2*)(proj + (size_t)card * 1536 + tp * 256 + p * 2);
      float2 vf = __half22float2(v2);
      float wv = wbar[side][h][jj];
      s0 += wv * vf.x;
      s1 += wv * vf.y;
    }
    __half2 o = __floats2half2_rn(s0, s1);
    *(__half2*)&meanf[(size_t)b * 512 + side * 256 + p * 2] = o;
  }
}

// ---------------------------------------------------------------------------
// K4: fused h1 GEMM (fp16 MFMA, BK=64) + bias + LN + ReLU + MFMA head + logit.
// M=16384,N=256,K=512. Block tile 32x256. h1 never leaves LDS.
// Head h2 = relu(h1@w2^T+b2) done as fp16 MFMA (2 row-tiles x 4 col-tiles),
// logit reduced via shfl + tiny LDS partial.
// ---------------------------------------------------------------------------
#define G4K 72
__global__ __launch_bounds__(256) void gemm_ln_head(
    const __half* __restrict__ meanf, const __half* __restrict__ wcf,
    const float* __restrict__ bias_c,
    const float* __restrict__ ln_g, const float* __restrict__ ln_b,
    const __half* __restrict__ w2h, const float* __restrict__ b2,
    const float* __restrict__ w3, const float* __restrict__ b3,
    float* __restrict__ out) {
  __shared__ __align__(16) char smem[41472];
  __half* sA = (__half*)smem;                  // 32*72 halves  (4608 B)
  __half* sB = sA + 32 * G4K;                  // 256*72 halves (36864 B)
  float* h1s = (float*)smem;                   // reused post-GEMM: 32 x 260 f32
  float* partial = (float*)(smem + 33280);     // 64 floats (dead sB region)

  int m0 = blockIdx.x * 32;
  int tid = threadIdx.x;
  int w = tid >> 6, lane = tid & 63;
  int lrow = lane & 15, lq = lane >> 4;
  int cb = w * 64;

  f32x4 acc[2][4] = {};

  for (int it = 0; it < 8; ++it) {
    int kb = it * 64;
    {
      int row = tid >> 3, p = tid & 7;   // 32 rows x 8 x 16B
      *(uint4*)&sA[row * G4K + p * 8] =
          *(const uint4*)&meanf[(size_t)(m0 + row) * 512 + kb + p * 8];
    }
#pragma unroll
    for (int rep = 0; rep < 8; ++rep) {
      int idx = rep * 256 + tid;         // 0..2047: 256 rows x 8 x 16B
      int n = idx >> 3, p = idx & 7;
      *(uint4*)&sB[n * G4K + p * 8] =
          *(const uint4*)&wcf[(size_t)n * 512 + kb + p * 8];
    }
    __syncthreads();
#pragma unroll
    for (int ks = 0; ks < 2; ++ks) {
      int ko = ks * 32 + lq * 8;
      half8 a[2];
#pragma unroll
      for (int t = 0; t < 2; ++t)
        a[t] = *(const half8*)&sA[(t * 16 + lrow) * G4K + ko];
#pragma unroll
      for (int j = 0; j < 4; ++j) {
        half8 bv = *(const half8*)&sB[(cb + j * 16 + lrow) * G4K + ko];
#pragma unroll
        for (int t = 0; t < 2; ++t)
          acc[t][j] = mfmaf16(a[t], bv, acc[t][j]);
      }
    }
    __syncthreads();
  }

  // h1 (+bias) into LDS
#pragma unroll
  for (int t = 0; t < 2; ++t)
#pragma unroll
    for (int j = 0; j < 4; ++j) {
      int col = cb + j * 16 + lrow;
      float bv = bias_c[col];
#pragma unroll
      for (int r = 0; r < 4; ++r) {
        int row = t * 16 + lq * 4 + r;
        h1s[row * 260 + col] = acc[t][j][r] + bv;
      }
    }
  __syncthreads();

  // LN + ReLU in place (wave w owns rows w*8..w*8+7)
  float g[4], bb[4];
#pragma unroll
  for (int s = 0; s < 4; ++s) {
    g[s]  = ln_g[lane + s * 64];
    bb[s] = ln_b[lane + s * 64];
  }
  for (int q = 0; q < 8; ++q) {
    int row = w * 8 + q;
    float v[4]; float sum = 0.f, ss = 0.f;
#pragma unroll
    for (int s = 0; s < 4; ++s) {
      v[s] = h1s[row * 260 + lane + s * 64];
      sum += v[s]; ss += v[s] * v[s];
    }
    for (int m = 1; m < 64; m <<= 1) {
      sum += __shfl_xor(sum, m);
      ss  += __shfl_xor(ss, m);
    }
    float mu = sum * (1.f / 256.f);
    float rs = rsqrtf(ss * (1.f / 256.f) - mu * mu + 1e-5f);
#pragma unroll
    for (int s = 0; s < 4; ++s) {
      float o = fmaxf((v[s] - mu) * rs * g[s] + bb[s], 0.f);
      h1s[row * 260 + lane + s * 64] = o;
    }
  }
  __syncthreads();

  // MFMA head: wave w -> row-tile rt = w>>1 (16 rows), col-pair cp = w&1
  // (cols cp*32..cp*32+31). h2 = relu(h1@w2^T + b2); logit += h2*w3.
  {
    int rt = w >> 1, cp = w & 1;
    f32x4 hacc[2] = {};
#pragma unroll
    for (int ks = 0; ks < 8; ++ks) {
      const float* ap = &h1s[(rt * 16 + lrow) * 260 + ks * 32 + lq * 8];
      float4 f0 = *(const float4*)ap;
      float4 f1 = *(const float4*)(ap + 4);
      half8 a;
      a[0] = (_Float16)f0.x; a[1] = (_Float16)f0.y;
      a[2] = (_Float16)f0.z; a[3] = (_Float16)f0.w;
      a[4] = (_Float16)f1.x; a[5] = (_Float16)f1.y;
      a[6] = (_Float16)f1.z; a[7] = (_Float16)f1.w;
#pragma unroll
      for (int j = 0; j < 2; ++j) {
        int n = cp * 32 + j * 16 + lrow;
        half8 bv = *(const half8*)&w2h[(size_t)n * 256 + ks * 32 + lq * 8];
        hacc[j] = mfmaf16(a, bv, hacc[j]);
      }
    }
    // epilogue: relu(+b2) * w3, reduce over the 32 cols this wave owns
    float s[4] = {0.f, 0.f, 0.f, 0.f};
#pragma unroll
    for (int j = 0; j < 2; ++j) {
      int n = cp * 32 + j * 16 + lrow;
      float b2v = b2[n], w3v = w3[n];
#pragma unroll
      for (int r = 0; r < 4; ++r)
        s[r] += fmaxf(hacc[j][r] + b2v, 0.f) * w3v;
    }
#pragma unroll
    for (int r = 0; r < 4; ++r) {
      s[r] += __shfl_xor(s[r], 1);
      s[r] += __shfl_xor(s[r], 2);
      s[r] += __shfl_xor(s[r], 4);
      s[r] += __shfl_xor(s[r], 8);
    }
    if (lrow == 0) {
#pragma unroll
      for (int r = 0; r < 4; ++r)
        partial[cp * 32 + rt * 16 + lq * 4 + r] = s[r];
    }
  }
  __syncthreads();
  if (tid < 32)
    out[m0 + tid] = partial[tid] + partial[32 + tid] + b3[0];
}

// ---------------------------------------------------------------------------
extern "C" void kernel_launch(void* const* d_in, const int* in_sizes, int n_in,
                              void* d_out, int out_size, void* d_ws, size_t ws_size,
                              hipStream_t stream) {
  const float* x_real   = (const float*)d_in[0];
  const float* x_imag   = (const float*)d_in[1];
  const int*   my_decks = (const int*)d_in[2];
  const int*   op_decks = (const int*)d_in[3];
  const int*   adj      = (const int*)d_in[4];
  const float* in_w_my  = (const float*)d_in[5];
  const float* in_b_my  = (const float*)d_in[6];
  const float* out_w_my = (const float*)d_in[7];
  const float* out_b_my = (const float*)d_in[8];
  const float* in_w_op  = (const float*)d_in[9];
  const float* in_b_op  = (const float*)d_in[10];
  const float* out_w_op = (const float*)d_in[11];
  const float* out_b_op = (const float*)d_in[12];
  const float* w1       = (const float*)d_in[13];
  const float* b1       = (const float*)d_in[14];
  const float* ln_g     = (const float*)d_in[15];
  const float* ln_b     = (const float*)d_in[16];
  const float* w2       = (const float*)d_in[17];
  const float* b2       = (const float*)d_in[18];
  const float* w3       = (const float*)d_in[19];
  const float* b3       = (const float*)d_in[20];

  __half* projh  = (__half*)d_ws;            // 10000*1536 halves
  __half* meanf  = projh + 15360000;         // 16384*512
  __half* wcf    = meanf + 8388608;          // 256*512
  __half* embf   = wcf + 131072;             // 10000*256
  __half* wbf    = embf + 2560000;           // 1536*256
  float* bias_c  = (float*)(wbf + 393216);   // 256 floats
  __half* w2h    = (__half*)(bias_c + 256);  // 64*256 halves
  float* out     = (float*)d_out;

  prep_all<<<5448, 256, 0, stream>>>(x_real, x_imag, in_w_my, in_w_op, w2,
                                     embf, wbf, w2h);

  dim3 g2((N_CARDS + 127) / 128, 1536 / 128);
  proj_mfma<<<g2, 256, 0, stream>>>(embf, wbf, in_b_my, in_b_op, projh);

  combine_w<<<dim3(257, 2), 256, 0, stream>>>(w1, b1, out_w_my, out_w_op,
                                              out_b_my, out_b_op, wcf, bias_c);

  attn_kernel<<<BATCH, 256, 0, stream>>>(projh, my_decks, op_decks, adj, meanf);

  gemm_ln_head<<<BATCH / 32, 256, 0, stream>>>(meanf, wcf, bias_c,
                                               ln_g, ln_b, w2h, b2, w3, b3, out);
}

// Round 2
// 598.323 us; speedup vs baseline: 1.0482x; 1.0076x over previous
//
#include <hip/hip_runtime.h>
#include <hip/hip_bf16.h>
#include <hip/hip_fp16.h>
#include <math.h>

// Problem constants
#define N_CARDS 10000
#define HIDDEN  128
#define E       256
#define BATCH   16384
#define L       8
#define NH      4
#define HD      64

typedef __attribute__((ext_vector_type(8))) short short8;
typedef __attribute__((ext_vector_type(4))) float f32x4;
typedef _Float16 __attribute__((ext_vector_type(8))) half8;
typedef _Float16 __attribute__((ext_vector_type(2))) h2v;
typedef unsigned short ust;

__device__ __forceinline__ f32x4 mfmaf16(half8 a, half8 b, f32x4 c) {
  return __builtin_amdgcn_mfma_f32_16x16x32_f16(a, b, c, 0, 0, 0);
}

// fp16 dot over 64 dims, f32 accumulate (v_dot2_f32_f16 when available)
__device__ __forceinline__ float dot64(const __half* q, const __half* k) {
  float s = 0.f;
#pragma unroll
  for (int d = 0; d < 8; ++d) {
    short8 qa = *(const short8*)(q + d * 8);
    short8 kb = *(const short8*)(k + d * 8);
    const h2v* q2 = (const h2v*)&qa;
    const h2v* k2 = (const h2v*)&kb;
#pragma unroll
    for (int m = 0; m < 4; ++m) {
#if __has_builtin(__builtin_amdgcn_fdot2)
      s = __builtin_amdgcn_fdot2(q2[m], k2[m], s, false);
#else
      s += (float)q2[m][0] * (float)k2[m][0] + (float)q2[m][1] * (float)k2[m][1];
#endif
    }
  }
  return s;
}

// ---------------------------------------------------------------------------
// K1: fused prep: emb->fp16 (blocks 0..4999), in_w->fp16 (5000..5383),
// w2 -> fp16 row-major copy (5384..5447), combine_w folded in (5448..5961).
// combine_w reads only original inputs -> no dependency on earlier blocks.
// ---------------------------------------------------------------------------
__global__ __launch_bounds__(256) void prep_all(
    const float* __restrict__ xr, const float* __restrict__ xi,
    const float* __restrict__ wmy, const float* __restrict__ wop,
    const float* __restrict__ w2,
    const float* __restrict__ w1, const float* __restrict__ b1,
    const float* __restrict__ owmy, const float* __restrict__ owop,
    const float* __restrict__ obm, const float* __restrict__ obo,
    __half* __restrict__ embf, __half* __restrict__ wbf,
    __half* __restrict__ w2h,
    __half* __restrict__ wcf, float* __restrict__ bias_c) {
  int bid = blockIdx.x;
  int tid = threadIdx.x;
  if (bid < 5000) {
    int c = bid * 2 + (tid >> 7);
    int d = tid & 127;
    float r  = xr[c * HIDDEN + d];
    float im = xi[c * HIDDEN + d];
    float amp = sqrtf(r * r + im * im + 1e-8f);
    float ph  = atan2f(im, r);
    embf[c * E + d]          = __float2half(amp);
    embf[c * E + HIDDEN + d] = __float2half(ph);
  } else if (bid < 5384) {
    int idx = (bid - 5000) * 256 + tid;   // float4 over 1536*256/4
    int row = idx >> 6, c4 = idx & 63;
    const float* src = (row < 768) ? (wmy + (size_t)row * 256)
                                   : (wop + (size_t)(row - 768) * 256);
    float4 v = *(const float4*)(src + c4 * 4);
    __half h[4] = {__float2half(v.x), __float2half(v.y),
                   __float2half(v.z), __float2half(v.w)};
    *(uint2*)&wbf[(size_t)row * 256 + c4 * 4] = *(const uint2*)h;
  } else if (bid < 5448) {
    int idx = (bid - 5384) * 256 + tid;   // 0..16383 over w2[64][256]
    w2h[idx] = __float2half(w2[idx]);
  } else {
    // combine_w: cid in [0,514): i = cid>>1, half_ = cid&1; i==256 -> bias_c
    int cid = bid - 5448;
    int i = cid >> 1;
    int half_ = cid & 1;
    if (i == 256) {
      if (half_) return;
      int t = threadIdx.x;
      float s = b1[t];
      for (int f = 0; f < 256; f += 4) {
        float4 wa = *(const float4*)&w1[(size_t)t * 512 + f];
        float4 ba = *(const float4*)&obm[f];
        float4 wb = *(const float4*)&w1[(size_t)t * 512 + 256 + f];
        float4 bo = *(const float4*)&obo[f];
        s += wa.x * ba.x + wa.y * ba.y + wa.z * ba.z + wa.w * ba.w;
        s += wb.x * bo.x + wb.y * bo.y + wb.z * bo.z + wb.w * bo.w;
      }
      bias_c[t] = s;
      return;
    }
    int kp = threadIdx.x;
    const float* ow = half_ ? owop : owmy;
    const float* w1r = w1 + (size_t)i * 512 + half_ * 256;
    float s0 = 0.f, s1 = 0.f, s2 = 0.f, s3 = 0.f;
    for (int f = 0; f < 256; f += 4) {
      s0 += w1r[f + 0] * ow[(size_t)(f + 0) * 256 + kp];
      s1 += w1r[f + 1] * ow[(size_t)(f + 1) * 256 + kp];
      s2 += w1r[f + 2] * ow[(size_t)(f + 2) * 256 + kp];
      s3 += w1r[f + 3] * ow[(size_t)(f + 3) * 256 + kp];
    }
    wcf[(size_t)i * 512 + half_ * 256 + kp] = __float2half((s0 + s1) + (s2 + s3));
  }
}

// ---------------------------------------------------------------------------
// K2: projection GEMM, pure fp16 MFMA (f32 accumulate); OUTPUT FP16.
// 128x128 tile, BK=64, 4 waves 2x2, 4x4 MFMA. LDS 36 KB -> 4 blocks/CU.
// ---------------------------------------------------------------------------
#define PSTR 72
__global__ __launch_bounds__(256) void proj_mfma(
    const __half* __restrict__ embf, const __half* __restrict__ wbf,
    const float* __restrict__ bmy, const float* __restrict__ bop,
    __half* __restrict__ proj) {
  __shared__ __align__(16) __half sA[128 * PSTR];
  __shared__ __align__(16) __half sB[128 * PSTR];
  int m0 = blockIdx.x * 128;
  int n0 = blockIdx.y * 128;
  int tid = threadIdx.x;
  int w = tid >> 6, lane = tid & 63;
  int wm = w >> 1, wn = w & 1;
  int lrow = lane & 15, lq = lane >> 4;

  f32x4 acc[4][4] = {};

  for (int kb = 0; kb < 256; kb += 64) {
#pragma unroll
    for (int rep = 0; rep < 4; ++rep) {
      int idx = rep * 256 + tid;       // 0..1023
      int row = idx >> 3, ch = (idx & 7) * 8;
      int gm = m0 + row;
      half8 av = {};
      if (gm < N_CARDS) av = *(const half8*)&embf[(size_t)gm * 256 + kb + ch];
      *(half8*)&sA[row * PSTR + ch] = av;
      int gn = n0 + row;
      *(half8*)&sB[row * PSTR + ch] = *(const half8*)&wbf[(size_t)gn * 256 + kb + ch];
    }
    __syncthreads();
#pragma unroll
    for (int ks = 0; ks < 2; ++ks) {
      int ko = ks * 32 + lq * 8;
      half8 a[4], b[4];
#pragma unroll
      for (int i = 0; i < 4; ++i) {
        a[i] = *(const half8*)&sA[(wm * 64 + i * 16 + lrow) * PSTR + ko];
        b[i] = *(const half8*)&sB[(wn * 64 + i * 16 + lrow) * PSTR + ko];
      }
#pragma unroll
      for (int i = 0; i < 4; ++i)
#pragma unroll
        for (int j = 0; j < 4; ++j)
          acc[i][j] = mfmaf16(a[i], b[j], acc[i][j]);
    }
    __syncthreads();
  }

  const float* bias = (n0 < 768) ? bmy : bop;
  int nbase = (n0 < 768) ? n0 : n0 - 768;
#pragma unroll
  for (int j = 0; j < 4; ++j) {
    int ncol = wn * 64 + j * 16 + lrow;
    float bv = bias[nbase + ncol];
#pragma unroll
    for (int i = 0; i < 4; ++i) {
      int mrow0 = m0 + wm * 64 + i * 16 + lq * 4;
#pragma unroll
      for (int r = 0; r < 4; ++r) {
        int m = mrow0 + r;
        if (m < N_CARDS)
          proj[(size_t)m * 1536 + n0 + ncol] = __float2half(acc[i][j][r] + bv);
      }
    }
  }
}

// ---------------------------------------------------------------------------
// K3: per-batch attention, BARRIER-FREE. One wave owns one head end-to-end:
// gathers its head's 64-dim q/k columns into a private LDS slice, loads its
// own adj bias (transposed side via in-wave shfl), computes BOTH sides'
// scores interleaved (2x ILP on dot+softmax chains), softmax in registers,
// PV for its own head. No __syncthreads, no cross-wave coupling.
// ---------------------------------------------------------------------------
#define GST 72
__global__ __launch_bounds__(256) void attn_kernel(
    const __half* __restrict__ proj,
    const int* __restrict__ my_decks, const int* __restrict__ op_decks,
    const int* __restrict__ adj,
    __half* __restrict__ meanf) {
  __shared__ __align__(16) __half tab[4 * 32 * GST];   // 4 waves x 32 rows x GST
  int b = blockIdx.x;
  int tid = threadIdx.x;
  int w = tid >> 6, lane = tid & 63;
  __half* tw = &tab[w * 32 * GST];

  // cards into lanes 0..15 (my 0-7, op 8-15); L1-served after wave 0
  int card16 = 0;
  if (lane < 16) {
    const int* dp = (lane < 8) ? (my_decks + b * L + lane)
                               : (op_decks + b * L + lane - 8);
    card16 = *dp;
  }
  int i = lane >> 3, j = lane & 7;

  // per-lane adj bias for pair (my_i, op_j) — issue early (HBM random)
  int ci = __shfl(card16, i);
  int cj = __shfl(card16, 8 + j);
  int madj = adj[(size_t)ci * N_CARDS + cj];

  // gather this head's columns of qmy(0) kmy(1) qop(3) kop(4)
  // row layout: table t rows [t*8, t*8+8), 64 halves per row, stride GST
#pragma unroll
  for (int t = 0; t < 4; ++t) {
    const int tp = (t == 0) ? 0 : (t == 1) ? 1 : (t == 2) ? 3 : 4;
    int useMy = (t == 0) | (t == 3);
    int card = __shfl(card16, useMy ? i : 8 + i);   // r = i
    uint4 u = *(const uint4*)(proj + (size_t)card * 1536 + tp * 256 + w * 64 + j * 8);
    *(uint4*)&tw[(t * 8 + i) * GST + j * 8] = u;
  }

  float biasA = (madj > 0) ? 0.0f : -10000.0f;
  float biasB = __shfl(biasA, (j << 3) | i);   // adj(my_j, op_i)

  // both sides' scores, interleaved for ILP
  float s0 = dot64(&tw[(0 * 8 + i) * GST], &tw[(1 * 8 + j) * GST]);
  float s1 = dot64(&tw[(2 * 8 + i) * GST], &tw[(3 * 8 + j) * GST]);
  s0 = s0 * 0.125f + biasA;
  s1 = s1 * 0.125f + biasB;

  float m0 = s0, m1 = s1;
  m0 = fmaxf(m0, __shfl_xor(m0, 1));  m1 = fmaxf(m1, __shfl_xor(m1, 1));
  m0 = fmaxf(m0, __shfl_xor(m0, 2));  m1 = fmaxf(m1, __shfl_xor(m1, 2));
  m0 = fmaxf(m0, __shfl_xor(m0, 4));  m1 = fmaxf(m1, __shfl_xor(m1, 4));
  float e0 = __expf(s0 - m0), e1 = __expf(s1 - m1);
  float t0 = e0, t1 = e1;
  t0 += __shfl_xor(t0, 1);  t1 += __shfl_xor(t1, 1);
  t0 += __shfl_xor(t0, 2);  t1 += __shfl_xor(t1, 2);
  t0 += __shfl_xor(t0, 4);  t1 += __shfl_xor(t1, 4);
  float a0 = e0 * __builtin_amdgcn_rcpf(t0);
  float a1 = e1 * __builtin_amdgcn_rcpf(t1);
  // mean over query rows i (lane bits 3..5)
  a0 += __shfl_xor(a0, 8);   a1 += __shfl_xor(a1, 8);
  a0 += __shfl_xor(a0, 16);  a1 += __shfl_xor(a1, 16);
  a0 += __shfl_xor(a0, 32);  a1 += __shfl_xor(a1, 32);

  // PV for this head: lanes 0-31 -> side0 (my, v=blk2 of op cards),
  // lanes 32-63 -> side1 (op, v=blk5 of my cards); 2 dims per lane.
  int side = lane >> 5, d2 = lane & 31;
  float wv[8];
#pragma unroll
  for (int jj = 0; jj < 8; ++jj) {
    float wa = __shfl(a0, jj);    // lane jj holds abar0[j=jj]
    float wb = __shfl(a1, jj);
    wv[jj] = (side ? wb : wa) * 0.125f;
  }
  int tp = side ? 5 : 2;
  float acc0 = 0.f, acc1 = 0.f;
#pragma unroll
  for (int jj = 0; jj < 8; ++jj) {
    int card = __shfl(card16, side ? jj : 8 + jj);
    __half2 v2 = *(const __half2*)(proj + (size_t)card * 1536 + tp * 256 + w * 64 + d2 * 2);
    float2 vf = __half22float2(v2);
    acc0 += wv[jj] * vf.x;
    acc1 += wv[jj] * vf.y;
  }
  *(__half2*)&meanf[(size_t)b * 512 + side * 256 + w * 64 + d2 * 2] =
      __floats2half2_rn(acc0, acc1);
}

// ---------------------------------------------------------------------------
// K4: fused h1 GEMM (fp16 MFMA, BK=64) + bias + LN + ReLU + MFMA head + logit.
// M=16384,N=256,K=512. Block tile 32x256. h1 never leaves LDS.
// ---------------------------------------------------------------------------
#define G4K 72
__global__ __launch_bounds__(256) void gemm_ln_head(
    const __half* __restrict__ meanf, const __half* __restrict__ wcf,
    const float* __restrict__ bias_c,
    const float* __restrict__ ln_g, const float* __restrict__ ln_b,
    const __half* __restrict__ w2h, const float* __restrict__ b2,
    const float* __restrict__ w3, const float* __restrict__ b3,
    float* __restrict__ out) {
  __shared__ __align__(16) char smem[41472];
  __half* sA = (__half*)smem;                  // 32*72 halves  (4608 B)
  __half* sB = sA + 32 * G4K;                  // 256*72 halves (36864 B)
  float* h1s = (float*)smem;                   // reused post-GEMM: 32 x 260 f32
  float* partial = (float*)(smem + 33280);     // 64 floats (dead sB region)

  int m0 = blockIdx.x * 32;
  int tid = threadIdx.x;
  int w = tid >> 6, lane = tid & 63;
  int lrow = lane & 15, lq = lane >> 4;
  int cb = w * 64;

  f32x4 acc[2][4] = {};

  for (int it = 0; it < 8; ++it) {
    int kb = it * 64;
    {
      int row = tid >> 3, p = tid & 7;   // 32 rows x 8 x 16B
      *(uint4*)&sA[row * G4K + p * 8] =
          *(const uint4*)&meanf[(size_t)(m0 + row) * 512 + kb + p * 8];
    }
#pragma unroll
    for (int rep = 0; rep < 8; ++rep) {
      int idx = rep * 256 + tid;         // 0..2047: 256 rows x 8 x 16B
      int n = idx >> 3, p = idx & 7;
      *(uint4*)&sB[n * G4K + p * 8] =
          *(const uint4*)&wcf[(size_t)n * 512 + kb + p * 8];
    }
    __syncthreads();
#pragma unroll
    for (int ks = 0; ks < 2; ++ks) {
      int ko = ks * 32 + lq * 8;
      half8 a[2];
#pragma unroll
      for (int t = 0; t < 2; ++t)
        a[t] = *(const half8*)&sA[(t * 16 + lrow) * G4K + ko];
#pragma unroll
      for (int j = 0; j < 4; ++j) {
        half8 bv = *(const half8*)&sB[(cb + j * 16 + lrow) * G4K + ko];
#pragma unroll
        for (int t = 0; t < 2; ++t)
          acc[t][j] = mfmaf16(a[t], bv, acc[t][j]);
      }
    }
    __syncthreads();
  }

  // h1 (+bias) into LDS
#pragma unroll
  for (int t = 0; t < 2; ++t)
#pragma unroll
    for (int j = 0; j < 4; ++j) {
      int col = cb + j * 16 + lrow;
      float bv = bias_c[col];
#pragma unroll
      for (int r = 0; r < 4; ++r) {
        int row = t * 16 + lq * 4 + r;
        h1s[row * 260 + col] = acc[t][j][r] + bv;
      }
    }
  __syncthreads();

  // LN + ReLU in place (wave w owns rows w*8..w*8+7)
  float g[4], bb[4];
#pragma unroll
  for (int s = 0; s < 4; ++s) {
    g[s]  = ln_g[lane + s * 64];
    bb[s] = ln_b[lane + s * 64];
  }
  for (int q = 0; q < 8; ++q) {
    int row = w * 8 + q;
    float v[4]; float sum = 0.f, ss = 0.f;
#pragma unroll
    for (int s = 0; s < 4; ++s) {
      v[s] = h1s[row * 260 + lane + s * 64];
      sum += v[s]; ss += v[s] * v[s];
    }
    for (int m = 1; m < 64; m <<= 1) {
      sum += __shfl_xor(sum, m);
      ss  += __shfl_xor(ss, m);
    }
    float mu = sum * (1.f / 256.f);
    float rs = rsqrtf(ss * (1.f / 256.f) - mu * mu + 1e-5f);
#pragma unroll
    for (int s = 0; s < 4; ++s) {
      float o = fmaxf((v[s] - mu) * rs * g[s] + bb[s], 0.f);
      h1s[row * 260 + lane + s * 64] = o;
    }
  }
  __syncthreads();

  // MFMA head: wave w -> row-tile rt = w>>1 (16 rows), col-pair cp = w&1
  // (cols cp*32..cp*32+31). h2 = relu(h1@w2^T + b2); logit += h2*w3.
  {
    int rt = w >> 1, cp = w & 1;
    f32x4 hacc[2] = {};
#pragma unroll
    for (int ks = 0; ks < 8; ++ks) {
      const float* ap = &h1s[(rt * 16 + lrow) * 260 + ks * 32 + lq * 8];
      float4 f0 = *(const float4*)ap;
      float4 f1 = *(const float4*)(ap + 4);
      half8 a;
      a[0] = (_Float16)f0.x; a[1] = (_Float16)f0.y;
      a[2] = (_Float16)f0.z; a[3] = (_Float16)f0.w;
      a[4] = (_Float16)f1.x; a[5] = (_Float16)f1.y;
      a[6] = (_Float16)f1.z; a[7] = (_Float16)f1.w;
#pragma unroll
      for (int j = 0; j < 2; ++j) {
        int n = cp * 32 + j * 16 + lrow;
        half8 bv = *(const half8*)&w2h[(size_t)n * 256 + ks * 32 + lq * 8];
        hacc[j] = mfmaf16(a, bv, hacc[j]);
      }
    }
    // epilogue: relu(+b2) * w3, reduce over the 32 cols this wave owns
    float s[4] = {0.f, 0.f, 0.f, 0.f};
#pragma unroll
    for (int j = 0; j < 2; ++j) {
      int n = cp * 32 + j * 16 + lrow;
      float b2v = b2[n], w3v = w3[n];
#pragma unroll
      for (int r = 0; r < 4; ++r)
        s[r] += fmaxf(hacc[j][r] + b2v, 0.f) * w3v;
    }
#pragma unroll
    for (int r = 0; r < 4; ++r) {
      s[r] += __shfl_xor(s[r], 1);
      s[r] += __shfl_xor(s[r], 2);
      s[r] += __shfl_xor(s[r], 4);
      s[r] += __shfl_xor(s[r], 8);
    }
    if (lrow == 0) {
#pragma unroll
      for (int r = 0; r < 4; ++r)
        partial[cp * 32 + rt * 16 + lq * 4 + r] = s[r];
    }
  }
  __syncthreads();
  if (tid < 32)
    out[m0 + tid] = partial[tid] + partial[32 + tid] + b3[0];
}

// ---------------------------------------------------------------------------
extern "C" void kernel_launch(void* const* d_in, const int* in_sizes, int n_in,
                              void* d_out, int out_size, void* d_ws, size_t ws_size,
                              hipStream_t stream) {
  const float* x_real   = (const float*)d_in[0];
  const float* x_imag   = (const float*)d_in[1];
  const int*   my_decks = (const int*)d_in[2];
  const int*   op_decks = (const int*)d_in[3];
  const int*   adj      = (const int*)d_in[4];
  const float* in_w_my  = (const float*)d_in[5];
  const float* in_b_my  = (const float*)d_in[6];
  const float* out_w_my = (const float*)d_in[7];
  const float* out_b_my = (const float*)d_in[8];
  const float* in_w_op  = (const float*)d_in[9];
  const float* in_b_op  = (const float*)d_in[10];
  const float* out_w_op = (const float*)d_in[11];
  const float* out_b_op = (const float*)d_in[12];
  const float* w1       = (const float*)d_in[13];
  const float* b1       = (const float*)d_in[14];
  const float* ln_g     = (const float*)d_in[15];
  const float* ln_b     = (const float*)d_in[16];
  const float* w2       = (const float*)d_in[17];
  const float* b2       = (const float*)d_in[18];
  const float* w3       = (const float*)d_in[19];
  const float* b3       = (const float*)d_in[20];

  __half* projh  = (__half*)d_ws;            // 10000*1536 halves
  __half* meanf  = projh + 15360000;         // 16384*512
  __half* wcf    = meanf + 8388608;          // 256*512
  __half* embf   = wcf + 131072;             // 10000*256
  __half* wbf    = embf + 2560000;           // 1536*256
  float* bias_c  = (float*)(wbf + 393216);   // 256 floats
  __half* w2h    = (__half*)(bias_c + 256);  // 64*256 halves
  float* out     = (float*)d_out;

  prep_all<<<5962, 256, 0, stream>>>(x_real, x_imag, in_w_my, in_w_op, w2,
                                     w1, b1, out_w_my, out_w_op, out_b_my, out_b_op,
                                     embf, wbf, w2h, wcf, bias_c);

  dim3 g2((N_CARDS + 127) / 128, 1536 / 128);
  proj_mfma<<<g2, 256, 0, stream>>>(embf, wbf, in_b_my, in_b_op, projh);

  attn_kernel<<<BATCH, 256, 0, stream>>>(projh, my_decks, op_decks, adj, meanf);

  gemm_ln_head<<<BATCH / 32, 256, 0, stream>>>(meanf, wcf, bias_c,
                                               ln_g, ln_b, w2h, b2, w3, b3, out);
}